// Round 13
// baseline (248.043 us; speedup 1.0000x reference)
//
#include <hip/hip_runtime.h>
#include <math.h>

#define BATCH 4
#define TSEQ 2048
#define CDIM 1024
#define NHEAD 16
#define HDIM 64
#define M_ROWS (BATCH * TSEQ)   // 8192

typedef float f32x4 __attribute__((ext_vector_type(4)));
typedef __bf16 bf16x8 __attribute__((ext_vector_type(8)));
typedef unsigned int u32x4 __attribute__((ext_vector_type(4)));

typedef const __attribute__((address_space(1))) void gas_void;
typedef __attribute__((address_space(3))) void las_void;

static __device__ __forceinline__ unsigned short f2bf(float f) {
    unsigned int x = __float_as_uint(f);
    x += 0x7fffu + ((x >> 16) & 1u);
    return (unsigned short)(x >> 16);
}

// ---------------- merged prep: 3x fp32->bf16 cvt + RoPE table -----------------
// block ranges: [0,4096) x, [4096,5632) w_attn, [5632,6144) w_proj, [6144,6400) rope
__global__ void prep_kernel(const float* __restrict__ x, unsigned short* __restrict__ xb,
                            const float* __restrict__ wa, unsigned short* __restrict__ wab,
                            const float* __restrict__ wp, unsigned short* __restrict__ wpb,
                            float* __restrict__ cosT, float* __restrict__ sinT) {
    int blk = blockIdx.x;
    if (blk < 6144) {
        const float* in;
        unsigned short* out;
        int base;
        if (blk < 4096)      { in = x;  out = xb;  base = blk; }
        else if (blk < 5632) { in = wa; out = wab; base = blk - 4096; }
        else                 { in = wp; out = wpb; base = blk - 5632; }
        int i = (base * 256 + threadIdx.x) << 3;
        float4 a = *(const float4*)(in + i);
        float4 b = *(const float4*)(in + i + 4);
        union { unsigned short u[8]; u32x4 v; } pk;
        pk.u[0] = f2bf(a.x); pk.u[1] = f2bf(a.y); pk.u[2] = f2bf(a.z); pk.u[3] = f2bf(a.w);
        pk.u[4] = f2bf(b.x); pk.u[5] = f2bf(b.y); pk.u[6] = f2bf(b.z); pk.u[7] = f2bf(b.w);
        *(u32x4*)(out + i) = pk.v;
    } else {
        int idx = (blk - 6144) * 256 + threadIdx.x;   // TSEQ * 32
        int t = idx >> 5;
        int i = idx & 31;
        double inv = pow(10000.0, -((double)(2 * i)) / (double)HDIM);
        double ph = (double)t * inv;
        cosT[idx] = (float)cos(ph);
        sinT[idx] = (float)sin(ph);
    }
}

// ============ bf16 MFMA GEMM core (C = A * B^T), 128x128 tile, BK=64 ==========
// v5: LDS chunk swizzle -> conflict-free fragment reads (6.29M -> 0 measured).
// v8: simple 2-barrier loop with BK=64 -- 83.7 -> 78.2us (counted-vmcnt
//     pipelines both regressed: T4-at-2-phase regime gate).
// v9: t-loop fully unrolled (addr immediates) + bijective XCD swizzle in
//     callers. qkv dropped below attn (<75us).
#define GROW(p) (((p) & 64) + (((p) & 15) << 2) + (((p) >> 4) & 3))
#define GEMM_CORE(A_, B_, K_, bm_, bn_)                                          \
    const int tid = threadIdx.x;                                                 \
    const int w = tid >> 6, lane = tid & 63;                                     \
    const int l15 = lane & 15, quad = lane >> 4;                                 \
    const int wm = w >> 1, wn = w & 1;                                           \
    const int ksw = ((lane & 7) ^ ((lane >> 3) & 7)) << 3;                       \
    const int rx = l15 & 7;                                                      \
    const unsigned short* Ag[4]; const unsigned short* Bg[4];                    \
    unsigned short* Al[4]; unsigned short* Bl[4];                                \
    _Pragma("unroll")                                                            \
    for (int i = 0; i < 4; ++i) {                                                \
        const int row = (w << 5) + (i << 3) + (lane >> 3);                       \
        Ag[i] = A_ + (size_t)(bm_ + row) * K_ + ksw;                             \
        Bg[i] = B_ + (size_t)(bn_ + GROW(row)) * K_ + ksw;                       \
        Al[i] = As + row * 64 + ((lane & 7) << 3);                               \
        Bl[i] = Bs + row * 64 + ((lane & 7) << 3);                               \
    }                                                                            \
    f32x4 acc[4][4];                                                             \
    _Pragma("unroll")                                                            \
    for (int i = 0; i < 4; ++i)                                                  \
        _Pragma("unroll")                                                        \
        for (int j = 0; j < 4; ++j) acc[i][j] = (f32x4){0.f, 0.f, 0.f, 0.f};     \
    _Pragma("unroll")                                                            \
    for (int t = 0; t < K_ / 64; ++t) {                                          \
        _Pragma("unroll")                                                        \
        for (int i = 0; i < 4; ++i) {                                            \
            __builtin_amdgcn_global_load_lds((gas_void*)(Ag[i] + t * 64), (las_void*)Al[i], 16, 0, 0); \
            __builtin_amdgcn_global_load_lds((gas_void*)(Bg[i] + t * 64), (las_void*)Bl[i], 16, 0, 0); \
        }                                                                        \
        __syncthreads();                                                         \
        _Pragma("unroll")                                                        \
        for (int kk = 0; kk < 2; ++kk) {                                         \
            bf16x8 af[4], bf[4];                                                 \
            _Pragma("unroll")                                                    \
            for (int mi = 0; mi < 4; ++mi)                                       \
                af[mi] = __builtin_bit_cast(bf16x8,                              \
                    *(const u32x4*)(As + ((wm << 6) + (mi << 4) + l15) * 64 + ((((kk << 2) + quad) ^ rx) << 3))); \
            _Pragma("unroll")                                                    \
            for (int ni = 0; ni < 4; ++ni)                                       \
                bf[ni] = __builtin_bit_cast(bf16x8,                              \
                    *(const u32x4*)(Bs + ((wn << 6) + (ni << 4) + l15) * 64 + ((((kk << 2) + quad) ^ rx) << 3))); \
            _Pragma("unroll")                                                    \
            for (int mi = 0; mi < 4; ++mi)                                       \
                _Pragma("unroll")                                                \
                for (int ni = 0; ni < 4; ++ni)                                   \
                    acc[mi][ni] = __builtin_amdgcn_mfma_f32_16x16x32_bf16(af[mi], bf[ni], acc[mi][ni], 0, 0, 0); \
        }                                                                        \
        __syncthreads();                                                         \
    }

// ---------- QKV GEMM (M=8192, N=3072, K=1024) + fused RoPE/pack/V-transpose ---
// grid 24x64 = 1536 blocks; bijective XCD swizzle: XCD c owns 8 contiguous
// row-bands (x fastest within) -> A-panel resident per XCD.
__global__ __launch_bounds__(256) void gemm_qkv_fused(
        const unsigned short* __restrict__ A, const unsigned short* __restrict__ B,
        unsigned short* __restrict__ qb, unsigned short* __restrict__ kb,
        unsigned short* __restrict__ vb,
        const float* __restrict__ cosT, const float* __restrict__ sinT) {
    __shared__ __align__(16) unsigned short As[128 * 64];
    __shared__ __align__(16) unsigned short Bs[128 * 64];
    const int orig = blockIdx.y * 24 + blockIdx.x;
    const int swz  = (orig & 7) * 192 + (orig >> 3);
    const int bm = (swz / 24) << 7;
    const int bn = (swz % 24) << 7;
    GEMM_CORE(A, B, CDIM, bm, bn)

    const int nbase = bn + (wn << 6);
    const int mbase = bm + (wm << 6);
    const int b = mbase >> 11;
    const int tt0 = mbase & (TSEQ - 1);
    const int d0 = l15 << 2;          // 4 consecutive d per thread
    const int fi = l15 << 1;          // freq index base = d0/2

    if (nbase < 2 * CDIM) {
        const int isQ = (nbase < CDIM) ? 1 : 0;
        unsigned short* dst = isQ ? qb : kb;
        const float qs = isQ ? 0.18033688f : 1.0f;   // 0.125 * log2(e)
        const int h = (nbase & (CDIM - 1)) >> 6;
        unsigned short* hb = dst + (size_t)(b * NHEAD + h) * TSEQ * HDIM;
#pragma unroll
        for (int mi = 0; mi < 4; ++mi) {
#pragma unroll
            for (int r = 0; r < 4; ++r) {
                const int t = tt0 + (mi << 4) + (quad << 2) + r;
                float2 cc = *(const float2*)(cosT + (t << 5) + fi);
                float2 ss = *(const float2*)(sinT + (t << 5) + fi);
                float re0 = acc[mi][0][r], im0 = acc[mi][1][r];
                float re1 = acc[mi][2][r], im1 = acc[mi][3][r];
                union { unsigned short u[4]; uint2 v; } pk;
                pk.u[0] = f2bf((re0 * cc.x - im0 * ss.x) * qs);
                pk.u[1] = f2bf((re0 * ss.x + im0 * cc.x) * qs);
                pk.u[2] = f2bf((re1 * cc.y - im1 * ss.y) * qs);
                pk.u[3] = f2bf((re1 * ss.y + im1 * cc.y) * qs);
                *(uint2*)(hb + (size_t)t * HDIM + d0) = pk.v;
            }
        }
    } else {
        const int h = (nbase - 2 * CDIM) >> 6;
        unsigned short* hb = vb + (size_t)(b * NHEAD + h) * HDIM * TSEQ;
#pragma unroll
        for (int mi = 0; mi < 4; ++mi) {
            const int t0 = tt0 + (mi << 4) + (quad << 2);
#pragma unroll
            for (int ni = 0; ni < 4; ++ni) {
                const int d = d0 + ni;
                union { unsigned short u[4]; uint2 v; } pk;
#pragma unroll
                for (int r = 0; r < 4; ++r) pk.u[r] = f2bf(acc[mi][ni][r]);
                *(uint2*)(hb + (size_t)d * TSEQ + t0) = pk.v;
            }
        }
    }
}

// ---------- proj GEMM (M=8192, N=1024, K=1024), fp32 output, float4 stores ----
// grid 8x64 = 512 blocks; same XCD swizzle (64 ids/XCD = 8 row-bands).
__global__ __launch_bounds__(256) void gemm_proj(
        const unsigned short* __restrict__ A, const unsigned short* __restrict__ B,
        float* __restrict__ C) {
    __shared__ __align__(16) unsigned short As[128 * 64];
    __shared__ __align__(16) unsigned short Bs[128 * 64];
    const int orig = blockIdx.y * 8 + blockIdx.x;
    const int swz  = (orig & 7) * 64 + (orig >> 3);
    const int bm = (swz >> 3) << 7;
    const int bn = (swz & 7) << 7;
    GEMM_CORE(A, B, CDIM, bm, bn)

#pragma unroll
    for (int mi = 0; mi < 4; ++mi)
#pragma unroll
        for (int r = 0; r < 4; ++r) {
            const int row = bm + (wm << 6) + (mi << 4) + (quad << 2) + r;
            float4 v = make_float4(acc[mi][0][r], acc[mi][1][r], acc[mi][2][r], acc[mi][3][r]);
            *(float4*)(C + (size_t)row * CDIM + bn + (wn << 6) + (l15 << 2)) = v;
        }
}

// ---------------- Flash attention v8: att[2] pipeline (PV lag-1) --------------
// v4: S^T = mfma(A=K, B=Q); lane-local P fragments; Ps round-trip gone.
// v5: V-staging bank fix (conflicts -> 0); l = P*1 via MFMA-ones. 69.1us.
// v7 (REVERTED): s_setprio -> 74.7us (lockstep-block starvation, m190 regime).
// v8: break the per-wave serial chain QK->SM->PV (the 69 vs 37us MFMA-floor
//     gap; waves ALTERNATE pipes). PV retimed one tile back: each iter is
//     barrier; PV(j-1); QK(j); SM(j); stage(j+1); load(j+2). PV(j-1) is
//     independent of QK(j)/SM(j) -> per-wave MFMA work is one contiguous
//     72-MFMA cluster, SM VALU at tail; the co-wave's cluster covers it.
//     V: 4 LDS buffers (writer j -> Vs[(j+1)&3]; readers at j+-2; >=2
//     barriers between every hazard). K: double-buffered (unchanged proof).
//     ap ping-pong via NAMED apA/apB + unroll-4 body (all indices static,
//     rule #20). Tile accumulation order unchanged -> identical numerics.
//     LDS 48KB (2 blocks/CU).
#define KTILE 64
#define NKT (TSEQ / KTILE)   // 32 (peels hardcoded for 32)
#define QBLK 256
#define SWZ(row, ch) (((row) << 6) + ((((ch) ^ ((row) & 7))) << 3))

#define STAGE_KV(KSN, VSN) do {                                                  \
    *(u32x4*)&Ks[KSN][stK0] = kr[0];                                             \
    *(u32x4*)&Ks[KSN][stK1] = kr[1];                                             \
    *(uint2*)&Vs[VSN][stV00] = make_uint2(vr[0][0], vr[0][1]);                   \
    *(uint2*)&Vs[VSN][stV01] = make_uint2(vr[0][2], vr[0][3]);                   \
    *(uint2*)&Vs[VSN][stV10] = make_uint2(vr[1][0], vr[1][1]);                   \
    *(uint2*)&Vs[VSN][stV11] = make_uint2(vr[1][2], vr[1][3]);                   \
} while (0)

#define LOAD_KV(BASE) do {                                                       \
    _Pragma("unroll")                                                            \
    for (int l = 0; l < 2; ++l) {                                                \
        kr[l] = *(const u32x4*)(kbase + (size_t)((BASE) + sr + (l << 5)) * HDIM + sp); \
        vr[l] = *(const u32x4*)(vbase + (size_t)(fv + (l << 5)) * TSEQ + (BASE) + sp); \
    }                                                                            \
} while (0)

#define QK_SM(KSC, APO) do {                                                     \
    _Pragma("unroll")                                                            \
    for (int pvk = 0; pvk < 2; ++pvk) {                                          \
        f32x4 s[2][4];                                                           \
        _Pragma("unroll")                                                        \
        for (int mi2 = 0; mi2 < 2; ++mi2) {                                      \
            const int rowK = (pvk * 2 + mi2) * 16 + l15;                         \
            bf16x8 k0 = __builtin_bit_cast(bf16x8, *(const u32x4*)&Ks[KSC][SWZ(rowK, quad)]); \
            bf16x8 k1 = __builtin_bit_cast(bf16x8, *(const u32x4*)&Ks[KSC][SWZ(rowK, quad ^ 4)]); \
            _Pragma("unroll")                                                    \
            for (int ni = 0; ni < 4; ++ni) {                                     \
                f32x4 a2 = (f32x4){0.f, 0.f, 0.f, 0.f};                          \
                a2 = __builtin_amdgcn_mfma_f32_16x16x32_bf16(k0, aq[ni][0], a2, 0, 0, 0); \
                a2 = __builtin_amdgcn_mfma_f32_16x16x32_bf16(k1, aq[ni][1], a2, 0, 0, 0); \
                s[mi2][ni] = a2;                                                 \
            }                                                                    \
        }                                                                        \
        _Pragma("unroll")                                                        \
        for (int ni = 0; ni < 4; ++ni) {                                         \
            float p0[4], p1[4];                                                  \
            _Pragma("unroll")                                                    \
            for (int r = 0; r < 4; ++r) {                                        \
                p0[r] = __builtin_amdgcn_exp2f(s[0][ni][r]);                     \
                p1[r] = __builtin_amdgcn_exp2f(s[1][ni][r]);                     \
            }                                                                    \
            u32x4 pk;                                                            \
            pk[0] = __builtin_amdgcn_perm(__float_as_uint(p0[1]), __float_as_uint(p0[0]), 0x07060302u); \
            pk[1] = __builtin_amdgcn_perm(__float_as_uint(p0[3]), __float_as_uint(p0[2]), 0x07060302u); \
            pk[2] = __builtin_amdgcn_perm(__float_as_uint(p1[1]), __float_as_uint(p1[0]), 0x07060302u); \
            pk[3] = __builtin_amdgcn_perm(__float_as_uint(p1[3]), __float_as_uint(p1[2]), 0x07060302u); \
            APO[ni][pvk] = __builtin_bit_cast(bf16x8, pk);                       \
        }                                                                        \
    }                                                                            \
} while (0)

#define PV_L(VSP, API) do {                                                      \
    _Pragma("unroll")                                                            \
    for (int ni = 0; ni < 4; ++ni) {                                             \
        lac[ni] = __builtin_amdgcn_mfma_f32_16x16x32_bf16(API[ni][0], vone, lac[ni], 0, 0, 0); \
        lac[ni] = __builtin_amdgcn_mfma_f32_16x16x32_bf16(API[ni][1], vone, lac[ni], 0, 0, 0); \
    }                                                                            \
    _Pragma("unroll")                                                            \
    for (int nc = 0; nc < 4; ++nc) {                                             \
        const int rowV = nc * 16 + l15;                                          \
        _Pragma("unroll")                                                        \
        for (int kc = 0; kc < 2; ++kc) {                                         \
            bf16x8 bv = __builtin_bit_cast(bf16x8, *(const u32x4*)&Vs[VSP][SWZ(rowV, (kc << 2) + quad)]); \
            _Pragma("unroll")                                                    \
            for (int ni = 0; ni < 4; ++ni)                                       \
                o[ni][nc] = __builtin_amdgcn_mfma_f32_16x16x32_bf16(API[ni][kc], bv, o[ni][nc], 0, 0, 0); \
        }                                                                        \
    }                                                                            \
} while (0)

// one pipelined iteration j: PV of tile j-1 overlaps SM of tile j
#define ATTN_IT(JV, KSC, VSP, KSN, VSN, API, APO, DOST, DOLD) do {               \
    __syncthreads();                                                             \
    PV_L(VSP, API);                                                              \
    QK_SM(KSC, APO);                                                             \
    if (DOST) STAGE_KV(KSN, VSN);                                                \
    if (DOLD) LOAD_KV(((JV) + 2) * KTILE);                                       \
} while (0)

__global__ __launch_bounds__(256, 2) void attn_mfma(
        const unsigned short* __restrict__ qb, const unsigned short* __restrict__ kb,
        const unsigned short* __restrict__ vb, unsigned short* __restrict__ y) {
    const int bh = blockIdx.x;          // fast dim -> XCD L2 locality on K/V
    const int qt = blockIdx.y;
    const int b = bh >> 4, h = bh & 15;
    const int tid  = threadIdx.x;
    const int w    = tid >> 6;
    const int lane = tid & 63;
    const int l15  = lane & 15;
    const int quad = lane >> 4;

    __shared__ __align__(16) unsigned short Ks[2][KTILE * 64];
    __shared__ __align__(16) unsigned short Vs[4][HDIM * 64];

    // Q fragments (B-operand): aq[ni][kc] = Q[q=ni*16+l15][d=kc*32+quad*8+0..7]
    const size_t qoff = ((size_t)bh * TSEQ + qt * QBLK + w * 64) * HDIM;
    bf16x8 aq[4][2];
#pragma unroll
    for (int ni = 0; ni < 4; ++ni)
#pragma unroll
        for (int kc = 0; kc < 2; ++kc) {
            u32x4 v = *(const u32x4*)(qb + qoff + (size_t)(ni * 16 + l15) * HDIM + kc * 32 + quad * 8);
            aq[ni][kc] = __builtin_bit_cast(bf16x8, v);
        }

    // all-ones bf16x8 for the l = P*1 rowsum MFMA
    const u32x4 ones_u = (u32x4){0x3F803F80u, 0x3F803F80u, 0x3F803F80u, 0x3F803F80u};
    const bf16x8 vone = __builtin_bit_cast(bf16x8, ones_u);

    f32x4 o[4][4];
    f32x4 lac[4];   // lac[ni][r] = l[q = ni*16 + 4*quad + r] (all l15 lanes)
#pragma unroll
    for (int ni = 0; ni < 4; ++ni) {
        lac[ni] = (f32x4){0.f, 0.f, 0.f, 0.f};
#pragma unroll
        for (int nc = 0; nc < 4; ++nc) o[ni][nc] = (f32x4){0.f, 0.f, 0.f, 0.f};
    }

    const unsigned short* kbase = kb + (size_t)bh * TSEQ * HDIM;
    const unsigned short* vbase = vb + (size_t)bh * HDIM * TSEQ;

    const int sr = tid >> 3;        // 0..31 (second element: +32)
    const int s8 = tid & 7;
    const int sp = s8 << 3;         // global col 0..56
    // K staging: linear rows sr / sr+32, col chunk s8
    const int stK0 = SWZ(sr, s8);
    const int stK1 = SWZ(sr + 32, s8);
    // V row assignment: fv bit-remap so each quarter-wave's two rows differ in
    // e0 parity (bank fix); logical rows via sigma_d (row n <-> true d).
    const int fv = (sr & 24) | ((sr & 1) << 2) | ((sr >> 1) & 3);
    const int vrow0 = ((fv & 3) << 4) + (fv >> 2);
    const int vrow1 = vrow0 + 8;
    const int chV  = ((s8 >> 2) << 2) + ((s8 & 1) << 1);   // 4*(s>>2)+2*(s&1)
    const int offV = ((s8 >> 1) & 1) << 2;                 // 4*((s>>1)&1)
    const int e0 = vrow0 & 7;                              // == vrow1 & 7
    const int stV00 = (vrow0 << 6) + ((chV ^ e0) << 3) + offV;
    const int stV01 = (vrow0 << 6) + (((chV + 1) ^ e0) << 3) + offV;
    const int stV10 = (vrow1 << 6) + ((chV ^ e0) << 3) + offV;
    const int stV11 = (vrow1 << 6) + (((chV + 1) ^ e0) << 3) + offV;

    bf16x8 apA[4][2], apB[4][2];
    u32x4 kr[2], vr[2];

    // prologue: tile 0 -> Ks0/Vs0; load tile 1
    LOAD_KV(0);
    STAGE_KV(0, 0);
    LOAD_KV(KTILE);

    // j = 0 (peeled: no PV yet)
    __syncthreads();
    QK_SM(0, apA);
    STAGE_KV(1, 1);          // tile 1
    LOAD_KV(2 * KTILE);      // tile 2

    // main: j = kt..kt+3 for kt = 1,5,...,25  (covers j = 1..28)
    for (int kt = 1; kt < 29; kt += 4) {
        ATTN_IT(kt,     1, 0, 0, 2, apA, apB, true, true);
        ATTN_IT(kt + 1, 0, 1, 1, 3, apB, apA, true, true);
        ATTN_IT(kt + 2, 1, 2, 0, 0, apA, apB, true, true);
        ATTN_IT(kt + 3, 0, 3, 1, 1, apB, apA, true, true);
    }
    // peeled tail: j = 29, 30, 31
    ATTN_IT(29, 1, 0, 0, 2, apA, apB, true,  true);   // stages 30, loads 31
    ATTN_IT(30, 0, 1, 1, 3, apB, apA, true,  false);  // stages 31
    ATTN_IT(31, 1, 2, 0, 0, apA, apB, false, false);  // QK(31) + PV(30)
    // epilogue PV: tile 31 (Vs[31&3]=Vs[3], staged at j=30; barrier at j=31 top)
    PV_L(3, apB);

    // epilogue: O /= l; lac[ni][r] is already this lane's l[q] -- no shuffles
#pragma unroll
    for (int ni = 0; ni < 4; ++ni)
#pragma unroll
        for (int r = 0; r < 4; ++r) {
            float inv_l = 1.f / lac[ni][r];
            int t = qt * QBLK + w * 64 + ni * 16 + quad * 4 + r;
            unsigned short* row = y + (size_t)(b * TSEQ + t) * CDIM + h * HDIM;
            union { unsigned short u[4]; uint2 v; } pk;
#pragma unroll
            for (int nc = 0; nc < 4; ++nc) pk.u[nc] = f2bf(o[ni][nc][r] * inv_l);
            *(uint2*)(row + (l15 << 2)) = pk.v;
        }
}

extern "C" void kernel_launch(void* const* d_in, const int* in_sizes, int n_in,
                              void* d_out, int out_size, void* d_ws, size_t ws_size,
                              hipStream_t stream) {
    const float* x      = (const float*)d_in[0];
    const float* w_attn = (const float*)d_in[1];
    const float* w_proj = (const float*)d_in[2];
    float* out = (float*)d_out;

    unsigned short* xb  = (unsigned short*)d_ws;
    unsigned short* wab = xb  + (size_t)M_ROWS * CDIM;
    unsigned short* wpb = wab + (size_t)3 * CDIM * CDIM;
    unsigned short* qb  = wpb + (size_t)CDIM * CDIM;
    unsigned short* kb  = qb  + (size_t)BATCH * NHEAD * TSEQ * HDIM;
    unsigned short* vb  = kb  + (size_t)BATCH * NHEAD * TSEQ * HDIM;
    unsigned short* yb  = vb  + (size_t)BATCH * NHEAD * TSEQ * HDIM;
    float* cosT = (float*)(yb + (size_t)M_ROWS * CDIM);
    float* sinT = cosT + TSEQ * (HDIM / 2);

    prep_kernel<<<6400, 256, 0, stream>>>(x, xb, w_attn, wab, w_proj, wpb, cosT, sinT);

    dim3 g1(3 * CDIM / 128, M_ROWS / 128);
    gemm_qkv_fused<<<g1, 256, 0, stream>>>(xb, wab, qb, kb, vb, cosT, sinT);

    dim3 g2(BATCH * NHEAD, TSEQ / QBLK);
    attn_mfma<<<g2, 256, 0, stream>>>(qb, kb, vb, yb);

    dim3 g3(CDIM / 128, M_ROWS / 128);
    gemm_proj<<<g3, 256, 0, stream>>>(yb, wpb, out);
}

// Round 14
// 232.089 us; speedup vs baseline: 1.0687x; 1.0687x over previous
//
#include <hip/hip_runtime.h>
#include <math.h>

#define BATCH 4
#define TSEQ 2048
#define CDIM 1024
#define NHEAD 16
#define HDIM 64
#define M_ROWS (BATCH * TSEQ)   // 8192

typedef float f32x4 __attribute__((ext_vector_type(4)));
typedef __bf16 bf16x8 __attribute__((ext_vector_type(8)));
typedef unsigned int u32x4 __attribute__((ext_vector_type(4)));

typedef const __attribute__((address_space(1))) void gas_void;
typedef __attribute__((address_space(3))) void las_void;

static __device__ __forceinline__ unsigned short f2bf(float f) {
    unsigned int x = __float_as_uint(f);
    x += 0x7fffu + ((x >> 16) & 1u);
    return (unsigned short)(x >> 16);
}

// ---------------- merged prep: 3x fp32->bf16 cvt + RoPE table -----------------
// block ranges: [0,4096) x, [4096,5632) w_attn, [5632,6144) w_proj, [6144,6400) rope
__global__ void prep_kernel(const float* __restrict__ x, unsigned short* __restrict__ xb,
                            const float* __restrict__ wa, unsigned short* __restrict__ wab,
                            const float* __restrict__ wp, unsigned short* __restrict__ wpb,
                            float* __restrict__ cosT, float* __restrict__ sinT) {
    int blk = blockIdx.x;
    if (blk < 6144) {
        const float* in;
        unsigned short* out;
        int base;
        if (blk < 4096)      { in = x;  out = xb;  base = blk; }
        else if (blk < 5632) { in = wa; out = wab; base = blk - 4096; }
        else                 { in = wp; out = wpb; base = blk - 5632; }
        int i = (base * 256 + threadIdx.x) << 3;
        float4 a = *(const float4*)(in + i);
        float4 b = *(const float4*)(in + i + 4);
        union { unsigned short u[8]; u32x4 v; } pk;
        pk.u[0] = f2bf(a.x); pk.u[1] = f2bf(a.y); pk.u[2] = f2bf(a.z); pk.u[3] = f2bf(a.w);
        pk.u[4] = f2bf(b.x); pk.u[5] = f2bf(b.y); pk.u[6] = f2bf(b.z); pk.u[7] = f2bf(b.w);
        *(u32x4*)(out + i) = pk.v;
    } else {
        int idx = (blk - 6144) * 256 + threadIdx.x;   // TSEQ * 32
        int t = idx >> 5;
        int i = idx & 31;
        double inv = pow(10000.0, -((double)(2 * i)) / (double)HDIM);
        double ph = (double)t * inv;
        cosT[idx] = (float)cos(ph);
        sinT[idx] = (float)sin(ph);
    }
}

// ============ bf16 MFMA GEMM core (C = A * B^T), 128x128 tile, BK=64 ==========
// v5: LDS chunk swizzle -> conflict-free fragment reads (6.29M -> 0 measured).
// v8: simple 2-barrier loop with BK=64 -- 83.7 -> 78.2us (counted-vmcnt
//     pipelines both regressed: T4-at-2-phase regime gate).
// v9: t-loop fully unrolled (addr immediates) + bijective XCD swizzle in
//     callers. qkv dropped below attn (<75us).
#define GROW(p) (((p) & 64) + (((p) & 15) << 2) + (((p) >> 4) & 3))
#define GEMM_CORE(A_, B_, K_, bm_, bn_)                                          \
    const int tid = threadIdx.x;                                                 \
    const int w = tid >> 6, lane = tid & 63;                                     \
    const int l15 = lane & 15, quad = lane >> 4;                                 \
    const int wm = w >> 1, wn = w & 1;                                           \
    const int ksw = ((lane & 7) ^ ((lane >> 3) & 7)) << 3;                       \
    const int rx = l15 & 7;                                                      \
    const unsigned short* Ag[4]; const unsigned short* Bg[4];                    \
    unsigned short* Al[4]; unsigned short* Bl[4];                                \
    _Pragma("unroll")                                                            \
    for (int i = 0; i < 4; ++i) {                                                \
        const int row = (w << 5) + (i << 3) + (lane >> 3);                       \
        Ag[i] = A_ + (size_t)(bm_ + row) * K_ + ksw;                             \
        Bg[i] = B_ + (size_t)(bn_ + GROW(row)) * K_ + ksw;                       \
        Al[i] = As + row * 64 + ((lane & 7) << 3);                               \
        Bl[i] = Bs + row * 64 + ((lane & 7) << 3);                               \
    }                                                                            \
    f32x4 acc[4][4];                                                             \
    _Pragma("unroll")                                                            \
    for (int i = 0; i < 4; ++i)                                                  \
        _Pragma("unroll")                                                        \
        for (int j = 0; j < 4; ++j) acc[i][j] = (f32x4){0.f, 0.f, 0.f, 0.f};     \
    _Pragma("unroll")                                                            \
    for (int t = 0; t < K_ / 64; ++t) {                                          \
        _Pragma("unroll")                                                        \
        for (int i = 0; i < 4; ++i) {                                            \
            __builtin_amdgcn_global_load_lds((gas_void*)(Ag[i] + t * 64), (las_void*)Al[i], 16, 0, 0); \
            __builtin_amdgcn_global_load_lds((gas_void*)(Bg[i] + t * 64), (las_void*)Bl[i], 16, 0, 0); \
        }                                                                        \
        __syncthreads();                                                         \
        _Pragma("unroll")                                                        \
        for (int kk = 0; kk < 2; ++kk) {                                         \
            bf16x8 af[4], bf[4];                                                 \
            _Pragma("unroll")                                                    \
            for (int mi = 0; mi < 4; ++mi)                                       \
                af[mi] = __builtin_bit_cast(bf16x8,                              \
                    *(const u32x4*)(As + ((wm << 6) + (mi << 4) + l15) * 64 + ((((kk << 2) + quad) ^ rx) << 3))); \
            _Pragma("unroll")                                                    \
            for (int ni = 0; ni < 4; ++ni)                                       \
                bf[ni] = __builtin_bit_cast(bf16x8,                              \
                    *(const u32x4*)(Bs + ((wn << 6) + (ni << 4) + l15) * 64 + ((((kk << 2) + quad) ^ rx) << 3))); \
            _Pragma("unroll")                                                    \
            for (int mi = 0; mi < 4; ++mi)                                       \
                _Pragma("unroll")                                                \
                for (int ni = 0; ni < 4; ++ni)                                   \
                    acc[mi][ni] = __builtin_amdgcn_mfma_f32_16x16x32_bf16(af[mi], bf[ni], acc[mi][ni], 0, 0, 0); \
        }                                                                        \
        __syncthreads();                                                         \
    }

// ---------- QKV GEMM (M=8192, N=3072, K=1024) + fused RoPE/pack/V-transpose ---
// grid 24x64 = 1536 blocks; bijective XCD swizzle: XCD c owns 8 contiguous
// row-bands (x fastest within) -> A-panel resident per XCD.
__global__ __launch_bounds__(256) void gemm_qkv_fused(
        const unsigned short* __restrict__ A, const unsigned short* __restrict__ B,
        unsigned short* __restrict__ qb, unsigned short* __restrict__ kb,
        unsigned short* __restrict__ vb,
        const float* __restrict__ cosT, const float* __restrict__ sinT) {
    __shared__ __align__(16) unsigned short As[128 * 64];
    __shared__ __align__(16) unsigned short Bs[128 * 64];
    const int orig = blockIdx.y * 24 + blockIdx.x;
    const int swz  = (orig & 7) * 192 + (orig >> 3);
    const int bm = (swz / 24) << 7;
    const int bn = (swz % 24) << 7;
    GEMM_CORE(A, B, CDIM, bm, bn)

    const int nbase = bn + (wn << 6);
    const int mbase = bm + (wm << 6);
    const int b = mbase >> 11;
    const int tt0 = mbase & (TSEQ - 1);
    const int d0 = l15 << 2;          // 4 consecutive d per thread
    const int fi = l15 << 1;          // freq index base = d0/2

    if (nbase < 2 * CDIM) {
        const int isQ = (nbase < CDIM) ? 1 : 0;
        unsigned short* dst = isQ ? qb : kb;
        const float qs = isQ ? 0.18033688f : 1.0f;   // 0.125 * log2(e)
        const int h = (nbase & (CDIM - 1)) >> 6;
        unsigned short* hb = dst + (size_t)(b * NHEAD + h) * TSEQ * HDIM;
#pragma unroll
        for (int mi = 0; mi < 4; ++mi) {
#pragma unroll
            for (int r = 0; r < 4; ++r) {
                const int t = tt0 + (mi << 4) + (quad << 2) + r;
                float2 cc = *(const float2*)(cosT + (t << 5) + fi);
                float2 ss = *(const float2*)(sinT + (t << 5) + fi);
                float re0 = acc[mi][0][r], im0 = acc[mi][1][r];
                float re1 = acc[mi][2][r], im1 = acc[mi][3][r];
                union { unsigned short u[4]; uint2 v; } pk;
                pk.u[0] = f2bf((re0 * cc.x - im0 * ss.x) * qs);
                pk.u[1] = f2bf((re0 * ss.x + im0 * cc.x) * qs);
                pk.u[2] = f2bf((re1 * cc.y - im1 * ss.y) * qs);
                pk.u[3] = f2bf((re1 * ss.y + im1 * cc.y) * qs);
                *(uint2*)(hb + (size_t)t * HDIM + d0) = pk.v;
            }
        }
    } else {
        const int h = (nbase - 2 * CDIM) >> 6;
        unsigned short* hb = vb + (size_t)(b * NHEAD + h) * HDIM * TSEQ;
#pragma unroll
        for (int mi = 0; mi < 4; ++mi) {
            const int t0 = tt0 + (mi << 4) + (quad << 2);
#pragma unroll
            for (int ni = 0; ni < 4; ++ni) {
                const int d = d0 + ni;
                union { unsigned short u[4]; uint2 v; } pk;
#pragma unroll
                for (int r = 0; r < 4; ++r) pk.u[r] = f2bf(acc[mi][ni][r]);
                *(uint2*)(hb + (size_t)d * TSEQ + t0) = pk.v;
            }
        }
    }
}

// ---------- proj GEMM (M=8192, N=1024, K=1024), fp32 output, float4 stores ----
// grid 8x64 = 512 blocks; same XCD swizzle (64 ids/XCD = 8 row-bands).
__global__ __launch_bounds__(256) void gemm_proj(
        const unsigned short* __restrict__ A, const unsigned short* __restrict__ B,
        float* __restrict__ C) {
    __shared__ __align__(16) unsigned short As[128 * 64];
    __shared__ __align__(16) unsigned short Bs[128 * 64];
    const int orig = blockIdx.y * 8 + blockIdx.x;
    const int swz  = (orig & 7) * 64 + (orig >> 3);
    const int bm = (swz >> 3) << 7;
    const int bn = (swz & 7) << 7;
    GEMM_CORE(A, B, CDIM, bm, bn)

#pragma unroll
    for (int mi = 0; mi < 4; ++mi)
#pragma unroll
        for (int r = 0; r < 4; ++r) {
            const int row = bm + (wm << 6) + (mi << 4) + (quad << 2) + r;
            float4 v = make_float4(acc[mi][0][r], acc[mi][1][r], acc[mi][2][r], acc[mi][3][r]);
            *(float4*)(C + (size_t)row * CDIM + bn + (wn << 6) + (l15 << 2)) = v;
        }
}

// ---------------- Flash attention v9: att[2] pipeline, corrected order --------
// v5: bank-fix + MFMA-ones rowsum. 69.1us (pipes ALTERNATE: 46+43=89%).
// v8 (BUG): PV lag-1 pipeline with STAGE/LOAD at iteration END -> the next
//     __syncthreads (which drains vmcnt(0)) ate the full global-load latency
//     with no compute cover: Mfma 37 + VALU 33 = 70%, 30% dead -> 87.2us.
// v9: same pipeline, memory-first order: barrier; STAGE(j+1); LOAD(j+2);
//     PV(j-1); QK_SM(j). Loads now have the 72-MFMA PV+QK cluster (~1500cyc)
//     before the next drain (v5's property), AND the per-wave MFMA work stays
//     one contiguous cluster with softmax at the tail (v8's property).
//     Hazards: STAGE targets Ks[(j+1)&1]/Vs[(j+1)&3]; last readers >=1/>=2
//     barriers back; staged kr/vr loaded a full iteration earlier; PV(j-1)
//     reads a different V buffer than staged. Numerics unchanged.
#define KTILE 64
#define NKT (TSEQ / KTILE)   // 32 (peels hardcoded for 32)
#define QBLK 256
#define SWZ(row, ch) (((row) << 6) + ((((ch) ^ ((row) & 7))) << 3))

#define STAGE_KV(KSN, VSN) do {                                                  \
    *(u32x4*)&Ks[KSN][stK0] = kr[0];                                             \
    *(u32x4*)&Ks[KSN][stK1] = kr[1];                                             \
    *(uint2*)&Vs[VSN][stV00] = make_uint2(vr[0][0], vr[0][1]);                   \
    *(uint2*)&Vs[VSN][stV01] = make_uint2(vr[0][2], vr[0][3]);                   \
    *(uint2*)&Vs[VSN][stV10] = make_uint2(vr[1][0], vr[1][1]);                   \
    *(uint2*)&Vs[VSN][stV11] = make_uint2(vr[1][2], vr[1][3]);                   \
} while (0)

#define LOAD_KV(BASE) do {                                                       \
    _Pragma("unroll")                                                            \
    for (int l = 0; l < 2; ++l) {                                                \
        kr[l] = *(const u32x4*)(kbase + (size_t)((BASE) + sr + (l << 5)) * HDIM + sp); \
        vr[l] = *(const u32x4*)(vbase + (size_t)(fv + (l << 5)) * TSEQ + (BASE) + sp); \
    }                                                                            \
} while (0)

#define QK_SM(KSC, APO) do {                                                     \
    _Pragma("unroll")                                                            \
    for (int pvk = 0; pvk < 2; ++pvk) {                                          \
        f32x4 s[2][4];                                                           \
        _Pragma("unroll")                                                        \
        for (int mi2 = 0; mi2 < 2; ++mi2) {                                      \
            const int rowK = (pvk * 2 + mi2) * 16 + l15;                         \
            bf16x8 k0 = __builtin_bit_cast(bf16x8, *(const u32x4*)&Ks[KSC][SWZ(rowK, quad)]); \
            bf16x8 k1 = __builtin_bit_cast(bf16x8, *(const u32x4*)&Ks[KSC][SWZ(rowK, quad ^ 4)]); \
            _Pragma("unroll")                                                    \
            for (int ni = 0; ni < 4; ++ni) {                                     \
                f32x4 a2 = (f32x4){0.f, 0.f, 0.f, 0.f};                          \
                a2 = __builtin_amdgcn_mfma_f32_16x16x32_bf16(k0, aq[ni][0], a2, 0, 0, 0); \
                a2 = __builtin_amdgcn_mfma_f32_16x16x32_bf16(k1, aq[ni][1], a2, 0, 0, 0); \
                s[mi2][ni] = a2;                                                 \
            }                                                                    \
        }                                                                        \
        _Pragma("unroll")                                                        \
        for (int ni = 0; ni < 4; ++ni) {                                         \
            float p0[4], p1[4];                                                  \
            _Pragma("unroll")                                                    \
            for (int r = 0; r < 4; ++r) {                                        \
                p0[r] = __builtin_amdgcn_exp2f(s[0][ni][r]);                     \
                p1[r] = __builtin_amdgcn_exp2f(s[1][ni][r]);                     \
            }                                                                    \
            u32x4 pk;                                                            \
            pk[0] = __builtin_amdgcn_perm(__float_as_uint(p0[1]), __float_as_uint(p0[0]), 0x07060302u); \
            pk[1] = __builtin_amdgcn_perm(__float_as_uint(p0[3]), __float_as_uint(p0[2]), 0x07060302u); \
            pk[2] = __builtin_amdgcn_perm(__float_as_uint(p1[1]), __float_as_uint(p1[0]), 0x07060302u); \
            pk[3] = __builtin_amdgcn_perm(__float_as_uint(p1[3]), __float_as_uint(p1[2]), 0x07060302u); \
            APO[ni][pvk] = __builtin_bit_cast(bf16x8, pk);                       \
        }                                                                        \
    }                                                                            \
} while (0)

#define PV_L(VSP, API) do {                                                      \
    _Pragma("unroll")                                                            \
    for (int ni = 0; ni < 4; ++ni) {                                             \
        lac[ni] = __builtin_amdgcn_mfma_f32_16x16x32_bf16(API[ni][0], vone, lac[ni], 0, 0, 0); \
        lac[ni] = __builtin_amdgcn_mfma_f32_16x16x32_bf16(API[ni][1], vone, lac[ni], 0, 0, 0); \
    }                                                                            \
    _Pragma("unroll")                                                            \
    for (int nc = 0; nc < 4; ++nc) {                                             \
        const int rowV = nc * 16 + l15;                                          \
        _Pragma("unroll")                                                        \
        for (int kc = 0; kc < 2; ++kc) {                                         \
            bf16x8 bv = __builtin_bit_cast(bf16x8, *(const u32x4*)&Vs[VSP][SWZ(rowV, (kc << 2) + quad)]); \
            _Pragma("unroll")                                                    \
            for (int ni = 0; ni < 4; ++ni)                                       \
                o[ni][nc] = __builtin_amdgcn_mfma_f32_16x16x32_bf16(API[ni][kc], bv, o[ni][nc], 0, 0, 0); \
        }                                                                        \
    }                                                                            \
} while (0)

// one pipelined iteration j: memory issue first, then PV(j-1) || SM(j)
#define ATTN_IT(JV, KSC, VSP, KSN, VSN, API, APO, DOST, DOLD) do {               \
    __syncthreads();                                                             \
    if (DOST) STAGE_KV(KSN, VSN);                                                \
    if (DOLD) LOAD_KV(((JV) + 2) * KTILE);                                       \
    PV_L(VSP, API);                                                              \
    QK_SM(KSC, APO);                                                             \
} while (0)

__global__ __launch_bounds__(256, 2) void attn_mfma(
        const unsigned short* __restrict__ qb, const unsigned short* __restrict__ kb,
        const unsigned short* __restrict__ vb, unsigned short* __restrict__ y) {
    const int bh = blockIdx.x;          // fast dim -> XCD L2 locality on K/V
    const int qt = blockIdx.y;
    const int b = bh >> 4, h = bh & 15;
    const int tid  = threadIdx.x;
    const int w    = tid >> 6;
    const int lane = tid & 63;
    const int l15  = lane & 15;
    const int quad = lane >> 4;

    __shared__ __align__(16) unsigned short Ks[2][KTILE * 64];
    __shared__ __align__(16) unsigned short Vs[4][HDIM * 64];

    // Q fragments (B-operand): aq[ni][kc] = Q[q=ni*16+l15][d=kc*32+quad*8+0..7]
    const size_t qoff = ((size_t)bh * TSEQ + qt * QBLK + w * 64) * HDIM;
    bf16x8 aq[4][2];
#pragma unroll
    for (int ni = 0; ni < 4; ++ni)
#pragma unroll
        for (int kc = 0; kc < 2; ++kc) {
            u32x4 v = *(const u32x4*)(qb + qoff + (size_t)(ni * 16 + l15) * HDIM + kc * 32 + quad * 8);
            aq[ni][kc] = __builtin_bit_cast(bf16x8, v);
        }

    // all-ones bf16x8 for the l = P*1 rowsum MFMA
    const u32x4 ones_u = (u32x4){0x3F803F80u, 0x3F803F80u, 0x3F803F80u, 0x3F803F80u};
    const bf16x8 vone = __builtin_bit_cast(bf16x8, ones_u);

    f32x4 o[4][4];
    f32x4 lac[4];   // lac[ni][r] = l[q = ni*16 + 4*quad + r] (all l15 lanes)
#pragma unroll
    for (int ni = 0; ni < 4; ++ni) {
        lac[ni] = (f32x4){0.f, 0.f, 0.f, 0.f};
#pragma unroll
        for (int nc = 0; nc < 4; ++nc) o[ni][nc] = (f32x4){0.f, 0.f, 0.f, 0.f};
    }

    const unsigned short* kbase = kb + (size_t)bh * TSEQ * HDIM;
    const unsigned short* vbase = vb + (size_t)bh * HDIM * TSEQ;

    const int sr = tid >> 3;        // 0..31 (second element: +32)
    const int s8 = tid & 7;
    const int sp = s8 << 3;         // global col 0..56
    // K staging: linear rows sr / sr+32, col chunk s8
    const int stK0 = SWZ(sr, s8);
    const int stK1 = SWZ(sr + 32, s8);
    // V row assignment: fv bit-remap so each quarter-wave's two rows differ in
    // e0 parity (bank fix); logical rows via sigma_d (row n <-> true d).
    const int fv = (sr & 24) | ((sr & 1) << 2) | ((sr >> 1) & 3);
    const int vrow0 = ((fv & 3) << 4) + (fv >> 2);
    const int vrow1 = vrow0 + 8;
    const int chV  = ((s8 >> 2) << 2) + ((s8 & 1) << 1);   // 4*(s>>2)+2*(s&1)
    const int offV = ((s8 >> 1) & 1) << 2;                 // 4*((s>>1)&1)
    const int e0 = vrow0 & 7;                              // == vrow1 & 7
    const int stV00 = (vrow0 << 6) + ((chV ^ e0) << 3) + offV;
    const int stV01 = (vrow0 << 6) + (((chV + 1) ^ e0) << 3) + offV;
    const int stV10 = (vrow1 << 6) + ((chV ^ e0) << 3) + offV;
    const int stV11 = (vrow1 << 6) + (((chV + 1) ^ e0) << 3) + offV;

    bf16x8 apA[4][2], apB[4][2];
    u32x4 kr[2], vr[2];

    // prologue: tile 0 -> Ks0/Vs0; load tile 1
    LOAD_KV(0);
    STAGE_KV(0, 0);
    LOAD_KV(KTILE);

    // j = 0 (peeled: no PV yet); memory-first order
    __syncthreads();
    STAGE_KV(1, 1);          // tile 1
    LOAD_KV(2 * KTILE);      // tile 2
    QK_SM(0, apA);

    // main: j = kt..kt+3 for kt = 1,5,...,25  (covers j = 1..28)
    for (int kt = 1; kt < 29; kt += 4) {
        ATTN_IT(kt,     1, 0, 0, 2, apA, apB, true, true);
        ATTN_IT(kt + 1, 0, 1, 1, 3, apB, apA, true, true);
        ATTN_IT(kt + 2, 1, 2, 0, 0, apA, apB, true, true);
        ATTN_IT(kt + 3, 0, 3, 1, 1, apB, apA, true, true);
    }
    // peeled tail: j = 29, 30, 31
    ATTN_IT(29, 1, 0, 0, 2, apA, apB, true,  true);   // stages 30, loads 31
    ATTN_IT(30, 0, 1, 1, 3, apB, apA, true,  false);  // stages 31
    ATTN_IT(31, 1, 2, 0, 0, apA, apB, false, false);  // QK(31) + PV(30)
    // epilogue PV: tile 31 (Vs[31&3]=Vs[3], staged at j=30; barrier at j=31 top)
    PV_L(3, apB);

    // epilogue: O /= l; lac[ni][r] is already this lane's l[q] -- no shuffles
#pragma unroll
    for (int ni = 0; ni < 4; ++ni)
#pragma unroll
        for (int r = 0; r < 4; ++r) {
            float inv_l = 1.f / lac[ni][r];
            int t = qt * QBLK + w * 64 + ni * 16 + quad * 4 + r;
            unsigned short* row = y + (size_t)(b * TSEQ + t) * CDIM + h * HDIM;
            union { unsigned short u[4]; uint2 v; } pk;
#pragma unroll
            for (int nc = 0; nc < 4; ++nc) pk.u[nc] = f2bf(o[ni][nc][r] * inv_l);
            *(uint2*)(row + (l15 << 2)) = pk.v;
        }
}

extern "C" void kernel_launch(void* const* d_in, const int* in_sizes, int n_in,
                              void* d_out, int out_size, void* d_ws, size_t ws_size,
                              hipStream_t stream) {
    const float* x      = (const float*)d_in[0];
    const float* w_attn = (const float*)d_in[1];
    const float* w_proj = (const float*)d_in[2];
    float* out = (float*)d_out;

    unsigned short* xb  = (unsigned short*)d_ws;
    unsigned short* wab = xb  + (size_t)M_ROWS * CDIM;
    unsigned short* wpb = wab + (size_t)3 * CDIM * CDIM;
    unsigned short* qb  = wpb + (size_t)CDIM * CDIM;
    unsigned short* kb  = qb  + (size_t)BATCH * NHEAD * TSEQ * HDIM;
    unsigned short* vb  = kb  + (size_t)BATCH * NHEAD * TSEQ * HDIM;
    unsigned short* yb  = vb  + (size_t)BATCH * NHEAD * TSEQ * HDIM;
    float* cosT = (float*)(yb + (size_t)M_ROWS * CDIM);
    float* sinT = cosT + TSEQ * (HDIM / 2);

    prep_kernel<<<6400, 256, 0, stream>>>(x, xb, w_attn, wab, w_proj, wpb, cosT, sinT);

    dim3 g1(3 * CDIM / 128, M_ROWS / 128);
    gemm_qkv_fused<<<g1, 256, 0, stream>>>(xb, wab, qb, kb, vb, cosT, sinT);

    dim3 g2(BATCH * NHEAD, TSEQ / QBLK);
    attn_mfma<<<g2, 256, 0, stream>>>(qb, kb, vb, yb);

    dim3 g3(CDIM / 128, M_ROWS / 128);
    gemm_proj<<<g3, 256, 0, stream>>>(yb, wpb, out);
}